// Round 2
// baseline (32.378 us; speedup 1.0000x reference)
//
#include <hip/hip_runtime.h>
#include <math.h>

// EdgeConstructor: out[b][i][j] = { dR(i,j), mass(i,j) } for B=256, N=256.
// Store-BW-bound: 134 MB f32 output. v2: float4 (16 B/lane) non-temporal
// stores, 2 columns/thread in registers, 2 rows/iteration.

#define BATCH 256
#define NN 256
#define TI 16  // rows per block

typedef float f4 __attribute__((ext_vector_type(4)));

__global__ __launch_bounds__(256)
void edge_kernel(const float* __restrict__ x, float* __restrict__ out) {
    const int b   = blockIdx.y;
    const int i0  = blockIdx.x * TI;
    const int tid = threadIdx.x;

    __shared__ float s_eta[NN], s_phi[NN], s_E[NN];
    __shared__ float s_px[NN], s_py[NN], s_pz[NN];

    // Phase 1: each thread precomputes node `tid` of batch b.
    const float4 v = reinterpret_cast<const float4*>(x)[b * NN + tid];
    {
        const float pt  = v.x;
        const float eta = v.y;
        const float phi = v.z;
        const float E   = v.w;
        float sp, cp;
        sincosf(phi, &sp, &cp);
        s_eta[tid] = eta; s_phi[tid] = phi; s_E[tid] = E;
        s_px[tid]  = pt * cp;
        s_py[tid]  = pt * sp;
        s_pz[tid]  = pt * sinhf(eta);
    }
    __syncthreads();

    const float PI         = 3.14159265358979323846f;
    const float TWO_PI     = 6.28318530717958647692f;
    const float INV_TWO_PI = 0.15915494309189533577f;

    // Phase 2: thread owns columns j0, j0+1; half the threads take even rows,
    // half take odd rows. One float4 (two edges) stored per iteration.
    const int half = tid >> 7;        // 0 or 1
    const int tc   = tid & 127;
    const int j0   = 2 * tc;

    // Column node values -> registers (stride-2 LDS reads: free 2-way)
    const float etaA = s_eta[j0],     etaB = s_eta[j0 + 1];
    const float phiA = s_phi[j0],     phiB = s_phi[j0 + 1];
    const float EA   = s_E[j0],       EB   = s_E[j0 + 1];
    const float pxA  = s_px[j0],      pxB  = s_px[j0 + 1];
    const float pyA  = s_py[j0],      pyB  = s_py[j0 + 1];
    const float pzA  = s_pz[j0],      pzB  = s_pz[j0 + 1];

    // float4 row stride = NN/2; base at (b, i0, j0)
    f4* orow = reinterpret_cast<f4*>(out)
             + ((size_t)(b * NN + i0) * NN) / 2 + tc;

#pragma unroll
    for (int k = 0; k < TI / 2; ++k) {
        const int i = i0 + 2 * k + half;
        // row-i values: wave-uniform LDS broadcast
        const float eta_i = s_eta[i];
        const float phi_i = s_phi[i];
        const float E_i   = s_E[i];
        const float px_i  = s_px[i];
        const float py_i  = s_py[i];
        const float pz_i  = s_pz[i];

        // pair (i, j0)
        const float detaA = eta_i - etaA;
        float tA = (phi_i - phiA) + PI;
        tA -= TWO_PI * floorf(tA * INV_TWO_PI);
        const float dphiA = tA - PI;
        const float dRA = sqrtf(fmaxf(fmaf(detaA, detaA, dphiA * dphiA), 1e-12f));
        const float esA  = E_i  + EA;
        const float pxsA = px_i + pxA;
        const float pysA = py_i + pyA;
        const float pzsA = pz_i + pzA;
        const float m2A  = esA * esA - pxsA * pxsA - pysA * pysA - pzsA * pzsA;
        const float mA   = sqrtf(fmaxf(m2A, 1e-12f));

        // pair (i, j0+1)
        const float detaB = eta_i - etaB;
        float tB = (phi_i - phiB) + PI;
        tB -= TWO_PI * floorf(tB * INV_TWO_PI);
        const float dphiB = tB - PI;
        const float dRB = sqrtf(fmaxf(fmaf(detaB, detaB, dphiB * dphiB), 1e-12f));
        const float esB  = E_i  + EB;
        const float pxsB = px_i + pxB;
        const float pysB = py_i + pyB;
        const float pzsB = pz_i + pzB;
        const float m2B  = esB * esB - pxsB * pxsB - pysB * pysB - pzsB * pzsB;
        const float mB   = sqrtf(fmaxf(m2B, 1e-12f));

        f4 o;
        o.x = dRA; o.y = mA; o.z = dRB; o.w = mB;
        __builtin_nontemporal_store(o, orow + (size_t)(2 * k + half) * (NN / 2));
    }
}

extern "C" void kernel_launch(void* const* d_in, const int* in_sizes, int n_in,
                              void* d_out, int out_size, void* d_ws, size_t ws_size,
                              hipStream_t stream) {
    const float* x = (const float*)d_in[0];
    float* out = (float*)d_out;
    dim3 grid(NN / TI, BATCH);
    dim3 block(256);
    edge_kernel<<<grid, block, 0, stream>>>(x, out);
}